// Round 2
// baseline (484.043 us; speedup 1.0000x reference)
//
#include <hip/hip_runtime.h>
#include <math.h>

#define IMG_H 512
#define IMG_W 512
#define TS 32
#define NC 5
#define NB 8

__device__ __forceinline__ int reflect_idx(int i, int n) {
    if (i < 0) i = -i;
    if (i >= n) i = 2 * n - 2 - i;
    return i;
}

__global__ __launch_bounds__(256)
void imnorm_kernel(const float* __restrict__ img, const float* __restrict__ bgr,
                   const float* __restrict__ thr, const float* __restrict__ scl,
                   float* __restrict__ out)
{
    const int plane = blockIdx.z;          // b*NC + c
    const int c = plane % NC;
    const int h0 = blockIdx.y * TS;
    const int w0 = blockIdx.x * TS;

    const float* x  = img + (size_t)plane * IMG_H * IMG_W;
    const float* bg = bgr + (size_t)plane * IMG_H * IMG_W;
    float* op = out + (size_t)plane * 7 * IMG_H * IMG_W;

    const int t = threadIdx.y * 32 + threadIdx.x;   // 0..255

    __shared__ float xs[48][48];   // x tile + halo 8, reflect-loaded
    __shared__ float h1[48][40];   // horizontal 9-sums of xs
    __shared__ float rs[40][40];   // res = x - box_mean(x), tile + halo 4
    __shared__ float h2[40][32];   // horizontal 9-sums of res^2 (reflect cols)

    // ---- stage 1: load x with reflect padding (2D reflect is separable) ----
    for (int i = t; i < 48 * 48; i += 256) {
        int r = i / 48, cc = i % 48;
        int gr = reflect_idx(h0 - 8 + r, IMG_H);
        int gc = reflect_idx(w0 - 8 + cc, IMG_W);
        xs[r][cc] = x[gr * IMG_W + gc];
    }
    __syncthreads();

    // ---- stage 2: horizontal 9-sum of xs -> h1 ----
    for (int i = t; i < 48 * 40; i += 256) {
        int r = i / 40, cl = i % 40;
        float s = 0.f;
        #pragma unroll
        for (int d = 0; d < 9; ++d) s += xs[r][cl + d];
        h1[r][cl] = s;
    }
    __syncthreads();

    // ---- stage 3: vertical 9-sum -> res over tile+halo4 ----
    // rs valid at all in-image positions (garbage at mirrored-out rows/cols,
    // but those are never read: stage 4/5 reflect back into valid coords).
    for (int i = t; i < 40 * 40; i += 256) {
        int rr = i / 40, cl = i % 40;
        float s = 0.f;
        #pragma unroll
        for (int d = 0; d < 9; ++d) s += h1[rr + d][cl];
        rs[rr][cl] = xs[rr + 4][cl + 4] - s * (1.0f / 81.0f);
    }
    __syncthreads();

    // ---- stage 4: horizontal 9-sum of res^2 with reflect on columns ----
    for (int i = t; i < 40 * 32; i += 256) {
        int rr = i / 32, wl = i % 32;
        float s = 0.f;
        #pragma unroll
        for (int d = 0; d < 9; ++d) {
            int gc = w0 + wl - 4 + d;
            int mc = reflect_idx(gc, IMG_W) - (w0 - 4);  // stays in [0,40)
            float v = rs[rr][mc];
            s += v * v;
        }
        h2[rr][wl] = s;
    }
    __syncthreads();

    // ---- stage 5: vertical 9-sum (reflect rows) + all elementwise channels ----
    float s_thr[3], s_exp[3];
    #pragma unroll
    for (int j = 0; j < 3; ++j) {
        s_thr[j] = thr[c * 3 + j];
        s_exp[j] = expf(scl[c * 3 + j]);
    }

    #pragma unroll
    for (int k = 0; k < 4; ++k) {
        const int hl = threadIdx.y + 8 * k;
        const int wl = threadIdx.x;
        const int h = h0 + hl, w = w0 + wl;

        float s = 0.f;
        #pragma unroll
        for (int d = 0; d < 9; ++d) {
            int gr = h - 4 + d;
            int mr = reflect_idx(gr, IMG_H) - (h0 - 4);  // stays in [0,40)
            s += h2[mr][wl];
        }
        float stdev = sqrtf(s * (1.0f / 81.0f));
        float resv  = rs[hl + 4][wl + 4];
        float clahe = resv / fmaxf(stdev, 1.0f);

        float raw = xs[hl + 8][wl + 8];
        float bgv = bg[h * IMG_W + w];
        float off0 = (raw - bgv) / sqrtf(bgv);
        float l0 = logf(fmaxf(off0 + 1.0f, 1.0f));   // t = 0
        float l1 = logf(fmaxf(off0, 1.0f));          // t = 1: (off0-1)+1

        const size_t base = (size_t)h * IMG_W + w;
        const size_t chs = (size_t)IMG_H * IMG_W;
        op[0 * chs + base] = raw;
        op[1 * chs + base] = l0;
        op[2 * chs + base] = l1;
        op[3 * chs + base] = clahe;
        #pragma unroll
        for (int j = 0; j < 3; ++j) {
            float v = (raw - s_thr[j]) * s_exp[j];
            op[(4 + j) * chs + base] = asinhf(v);
        }
    }
}

extern "C" void kernel_launch(void* const* d_in, const int* in_sizes, int n_in,
                              void* d_out, int out_size, void* d_ws, size_t ws_size,
                              hipStream_t stream) {
    const float* img = (const float*)d_in[0];
    const float* bg  = (const float*)d_in[1];
    const float* thr = (const float*)d_in[2];
    const float* scl = (const float*)d_in[3];
    float* out = (float*)d_out;

    dim3 grid(IMG_W / TS, IMG_H / TS, NB * NC);   // 16 x 16 x 40 = 10240 blocks
    dim3 block(32, 8);
    hipLaunchKernelGGL(imnorm_kernel, grid, block, 0, stream,
                       img, bg, thr, scl, out);
}